// Round 7
// baseline (89.038 us; speedup 1.0000x reference)
//
#include <hip/hip_runtime.h>
#include <stdint.h>

#define TPB 256
#define SELTPB 1024
#define SELWAVES (SELTPB / 64)
#define MAXNO 64
#define NMB 16  // match chunks per batch row

__device__ __forceinline__ float sl1f(float d) {
    float ad = fabsf(d);
    return ad < 1.0f ? 0.5f * d * d : ad - 0.5f;
}

__device__ __forceinline__ float iou_pair(float tx1, float ty1, float tx2, float ty2, float ta,
                                          float px1, float py1, float px2, float py2, float pa) {
    float ltx = fmaxf(tx1, px1), lty = fmaxf(ty1, py1);
    float rbx = fminf(tx2, px2), rby = fminf(ty2, py2);
    float wx = fmaxf(rbx - ltx, 0.0f), wy = fmaxf(rby - lty, 0.0f);
    float inter = wx * wy;
    return inter / ((ta + pa) - inter);
}

// Kernel A: per (b, chunk) partial argmax over that chunk's priors.
// key = (float_bits(iou) << 32) | (0xFFFFFFFF - p)  => max iou, tie -> min p.
template <int NO>
__global__ __launch_bounds__(256) void match_partial_kernel(
    const float* __restrict__ dbox, const float* __restrict__ targets,
    unsigned long long* __restrict__ pkeys, int Np, int No) {
    int b = blockIdx.y, mb = blockIdx.x;
    int tid = threadIdx.x;
    __shared__ float s_t[NO][5];  // x1,y1,x2,y2,area
    __shared__ unsigned long long s_k[4][NO];
    if (tid < No) {
        const float* tr = targets + ((size_t)b * No + tid) * 5;
        float x1 = tr[0], y1 = tr[1], x2 = tr[2], y2 = tr[3];
        s_t[tid][0] = x1; s_t[tid][1] = y1; s_t[tid][2] = x2; s_t[tid][3] = y2;
        s_t[tid][4] = (x2 - x1) * (y2 - y1);
    }
    __syncthreads();
    int clen = (Np + NMB - 1) / NMB;
    int start = mb * clen;
    int end = start + clen;
    if (end > Np) end = Np;
    unsigned long long key[NO];
#pragma unroll
    for (int t = 0; t < NO; ++t) key[t] = 0ull;
    for (int p = start + tid; p < end; p += 256) {
        float4 pr = *reinterpret_cast<const float4*>(dbox + (size_t)p * 4);
        float px1 = pr.x - pr.z * 0.5f, py1 = pr.y - pr.w * 0.5f;
        float px2 = pr.x + pr.z * 0.5f, py2 = pr.y + pr.w * 0.5f;
        float pa = (px2 - px1) * (py2 - py1);
        unsigned lowp = 0xFFFFFFFFu - (unsigned)p;
#pragma unroll
        for (int t = 0; t < NO; ++t) {
            float iou = iou_pair(s_t[t][0], s_t[t][1], s_t[t][2], s_t[t][3], s_t[t][4],
                                 px1, py1, px2, py2, pa);
            unsigned long long k =
                (((unsigned long long)__float_as_uint(iou)) << 32) | (unsigned long long)lowp;
            if (k > key[t]) key[t] = k;
        }
    }
    int lane = tid & 63, wv = tid >> 6;
#pragma unroll
    for (int t = 0; t < NO; ++t) {
        unsigned long long k = key[t];
        for (int off = 32; off; off >>= 1) {
            unsigned long long o = __shfl_down(k, off);
            if (o > k) k = o;
        }
        if (lane == 0) s_k[wv][t] = k;
    }
    __syncthreads();
    if (tid < No) {
        unsigned long long m = s_k[0][tid];
#pragma unroll
        for (int w = 1; w < 4; ++w)
            if (s_k[w][tid] > m) m = s_k[w][tid];
        pkeys[((size_t)b * NMB + mb) * No + tid] = m;
    }
}

// Kernel A2: fold partials and pack per-truth metadata (32B record):
// {x1,y1,x2,y2,area,label,ovr_prior(bits),0}. Tiny: B blocks x 64 threads.
__global__ __launch_bounds__(64) void combine_kernel(
    const unsigned long long* __restrict__ pkeys, const float* __restrict__ targets,
    float* __restrict__ tmeta, int No) {
    int b = blockIdx.x, t = threadIdx.x;
    if (t >= No) return;
    unsigned long long k = pkeys[((size_t)b * NMB + 0) * No + t];
    for (int m = 1; m < NMB; ++m) {
        unsigned long long kk = pkeys[((size_t)b * NMB + m) * No + t];
        if (kk > k) k = kk;
    }
    const float* tr = targets + ((size_t)b * No + t) * 5;
    float x1 = tr[0], y1 = tr[1], x2 = tr[2], y2 = tr[3];
    float* tm = tmeta + ((size_t)b * MAXNO + t) * 8;
    tm[0] = x1; tm[1] = y1; tm[2] = x2; tm[3] = y2;
    tm[4] = (x2 - x1) * (y2 - y1);
    tm[5] = tr[4];
    tm[6] = __uint_as_float(0xFFFFFFFFu - (unsigned)(k & 0xFFFFFFFFull));
    tm[7] = 0.0f;
}

// Kernel B (main): per prior. Truth metadata read via block-UNIFORM tmeta loads
// (SMEM scalar path, off the LDS pipe); only a tiny 16x5 LDS copy remains for
// the divergent bidx gather. Conf row via LDS staging + register cache.
template <int CC, int TNO>
__global__ __launch_bounds__(TPB) void main_kernel(
    const float* __restrict__ loc, const float* __restrict__ conf,
    const float* __restrict__ dbox, const float* __restrict__ tmeta,
    float* __restrict__ v, float* __restrict__ part_l, float* __restrict__ part_c,
    int* __restrict__ part_n, int Np, int C, int No, int nchunk) {
    extern __shared__ float s_conf[];  // TPB * C
    __shared__ float s_tb[MAXNO][5];   // x1,y1,x2,y2,label (divergent gather only)
    __shared__ float s_red1[4];
    __shared__ float s_red2[4];
    __shared__ int s_redi[4];
    int b = blockIdx.y, chunk = blockIdx.x, tid = threadIdx.x;
    int p = chunk * TPB + tid;
    bool valid = p < Np;
    if (tid < No) {
        const float* tm = tmeta + ((size_t)b * MAXNO + tid) * 8;
        s_tb[tid][0] = tm[0]; s_tb[tid][1] = tm[1];
        s_tb[tid][2] = tm[2]; s_tb[tid][3] = tm[3];
        s_tb[tid][4] = tm[5];
    }
    int pbase = chunk * TPB;
    int cnt = Np - pbase;
    if (cnt > TPB) cnt = TPB;
    const float* cbase = conf + ((size_t)b * Np + (size_t)pbase) * C;
    {
        int ntot = cnt * C;
        int nv4 = ntot >> 2;
        const float4* c4 = reinterpret_cast<const float4*>(cbase);
        float4* s4 = reinterpret_cast<float4*>(s_conf);
        for (int i = tid; i < nv4; i += TPB) s4[i] = c4[i];
        for (int i = (nv4 << 2) + tid; i < ntot; i += TPB) s_conf[i] = cbase[i];
    }
    __syncthreads();

    float lossl = 0.0f, posce = 0.0f;
    int npos = 0;
    if (valid) {
        float4 pr = *reinterpret_cast<const float4*>(dbox + (size_t)p * 4);
        float px1 = pr.x - pr.z * 0.5f, py1 = pr.y - pr.w * 0.5f;
        float px2 = pr.x + pr.z * 0.5f, py2 = pr.y + pr.w * 0.5f;
        float pa = (px2 - px1) * (py2 - py1);
        float bov = -1.0f;
        int bidx = 0;
        int ovt = -1;
        if (TNO > 0) {
#pragma unroll
            for (int t = 0; t < TNO; ++t) {
                const float* tm = tmeta + ((size_t)b * MAXNO + t) * 8;  // uniform -> s_load
                float iou = iou_pair(tm[0], tm[1], tm[2], tm[3], tm[4],
                                     px1, py1, px2, py2, pa);
                if (iou > bov) { bov = iou; bidx = t; }  // strict > : first occurrence
                if (__float_as_uint(tm[6]) == (unsigned)p) ovt = t;  // last match wins
            }
        } else {
            for (int t = 0; t < No; ++t) {
                const float* tm = tmeta + ((size_t)b * MAXNO + t) * 8;
                float iou = iou_pair(tm[0], tm[1], tm[2], tm[3], tm[4],
                                     px1, py1, px2, py2, pa);
                if (iou > bov) { bov = iou; bidx = t; }
                if (__float_as_uint(tm[6]) == (unsigned)p) ovt = t;
            }
        }
        if (ovt >= 0) { bidx = ovt; bov = 2.0f; }
        int ct = (bov < 0.5f) ? 0 : ((int)s_tb[bidx][4] + 1);
        float ce;
        if (CC > 0) {
            const float* crow = s_conf + tid * CC;
            float fr[CC > 0 ? CC : 1];
            float mx = -1e30f, fc = 0.0f;
#pragma unroll
            for (int j = 0; j < CC; ++j) {
                float x = crow[j];
                fr[j] = x;
                mx = fmaxf(mx, x);
                fc = (j == ct) ? x : fc;  // static-indexed select, no scratch
            }
            float s = 0.0f;
#pragma unroll
            for (int j = 0; j < CC; ++j) s += __expf(fr[j] - mx);
            ce = __logf(s) + mx - fc;
        } else {
            const float* crow = s_conf + (size_t)tid * C;
            float mx = crow[0];
            for (int j = 1; j < C; ++j) mx = fmaxf(mx, crow[j]);
            float s = 0.0f;
            for (int j = 0; j < C; ++j) s += __expf(crow[j] - mx);
            ce = __logf(s) + mx - crow[ct];
        }
        bool pos = ct > 0;
        v[(size_t)b * Np + p] = pos ? 0.0f : ce;
        if (pos) {
            posce = ce;
            npos = 1;
            float mx1 = s_tb[bidx][0], my1 = s_tb[bidx][1];
            float mx2 = s_tb[bidx][2], my2 = s_tb[bidx][3];
            float gcx = ((mx1 + mx2) * 0.5f - pr.x) / (0.1f * pr.z);
            float gcy = ((my1 + my2) * 0.5f - pr.y) / (0.1f * pr.w);
            float gw = __logf((mx2 - mx1) / pr.z) / 0.2f;
            float gh = __logf((my2 - my1) / pr.w) / 0.2f;
            float4 l4 = *reinterpret_cast<const float4*>(loc + ((size_t)b * Np + p) * 4);
            lossl = sl1f(l4.x - gcx) + sl1f(l4.y - gcy) + sl1f(l4.z - gw) + sl1f(l4.w - gh);
        }
    }
    // single fused fixed-order block reduction (deterministic)
    float a1 = lossl, a2 = posce;
    int ni = npos;
    for (int off = 32; off; off >>= 1) {
        a1 += __shfl_down(a1, off);
        a2 += __shfl_down(a2, off);
        ni += __shfl_down(ni, off);
    }
    if ((tid & 63) == 0) {
        s_red1[tid >> 6] = a1;
        s_red2[tid >> 6] = a2;
        s_redi[tid >> 6] = ni;
    }
    __syncthreads();
    if (tid == 0) {
        part_l[(size_t)b * nchunk + chunk] = s_red1[0] + s_red1[1] + s_red1[2] + s_red1[3];
        part_c[(size_t)b * nchunk + chunk] = s_red2[0] + s_red2[1] + s_red2[2] + s_red2[3];
        part_n[(size_t)b * nchunk + chunk] = s_redi[0] + s_redi[1] + s_redi[2] + s_redi[3];
    }
}

// Kernel C: per row b -- radix-select the K-th largest float-bits threshold over v,
// then loss_c = posce + sum_{v > T} v + Krem * T.
__global__ __launch_bounds__(SELTPB) void select_kernel(
    const float* __restrict__ v, const float* __restrict__ pl,
    const float* __restrict__ pc, const int* __restrict__ pn,
    float* __restrict__ row_res, int Np, int nchunk, int negpos) {
    int b = blockIdx.x, tid = threadIdx.x;
    int lane = tid & 63, wv = tid >> 6;
    extern __shared__ unsigned sv[];  // Np
    __shared__ unsigned whist[SELWAVES][256];  // per-wave privatized hist (16 KB)
    __shared__ unsigned suf[257];
    __shared__ float s_f[SELWAVES];
    __shared__ int s_dig, s_acc;
    __shared__ float s_lossl, s_posce;
    __shared__ int s_np;

    if (wv == 0) {
        float a = 0.0f, c = 0.0f;
        int n = 0;
        for (int i = lane; i < nchunk; i += 64) {
            a += pl[(size_t)b * nchunk + i];
            c += pc[(size_t)b * nchunk + i];
            n += pn[(size_t)b * nchunk + i];
        }
        for (int off = 32; off; off >>= 1) {
            a += __shfl_down(a, off);
            c += __shfl_down(c, off);
            n += __shfl_down(n, off);
        }
        if (lane == 0) { s_lossl = a; s_posce = c; s_np = n; }
    }
    {
        const float4* v4 = reinterpret_cast<const float4*>(v + (size_t)b * Np);
        int n4 = Np >> 2;
        for (int i = tid; i < n4; i += SELTPB) {
            float4 f = v4[i];
            uint4 u;
            u.x = __float_as_uint(f.x); u.y = __float_as_uint(f.y);
            u.z = __float_as_uint(f.z); u.w = __float_as_uint(f.w);
            *reinterpret_cast<uint4*>(&sv[i << 2]) = u;
        }
        for (int i = (n4 << 2) + tid; i < Np; i += SELTPB)
            sv[i] = __float_as_uint(v[(size_t)b * Np + i]);
    }
    __syncthreads();
    int npos = s_np;
    int K = npos * negpos;
    if (K > Np) K = Np;
    float lossc = s_posce;
    if (K > 0) {
        unsigned prefix = 0;
        int Krem = K;
        for (int shift = 24; shift >= 0; shift -= 8) {
            for (int i = tid; i < SELWAVES * 256; i += SELTPB)
                (&whist[0][0])[i] = 0;
            __syncthreads();
            for (int i = tid; i < Np; i += SELTPB) {
                unsigned u = sv[i];
                bool match = (shift == 24) || ((u >> (shift + 8)) == (prefix >> (shift + 8)));
                if (match) atomicAdd(&whist[wv][(u >> shift) & 0xFFu], 1u);
            }
            __syncthreads();
            if (tid < 256) {
                unsigned t = 0;
                for (int w = 0; w < SELWAVES; ++w) t += whist[w][tid];
                suf[tid] = t;
            }
            if (tid == 0) suf[256] = 0;
            __syncthreads();
            for (int off = 1; off < 256; off <<= 1) {
                unsigned add = 0;
                if (tid < 256 && tid + off < 256) add = suf[tid + off];
                __syncthreads();
                if (tid < 256) suf[tid] += add;
                __syncthreads();
            }
            if (tid < 256) {
                unsigned S = suf[tid];
                unsigned Snext = suf[tid + 1];
                if ((int)S >= Krem && (int)Snext < Krem) { s_dig = tid; s_acc = (int)Snext; }
            }
            __syncthreads();
            prefix |= ((unsigned)s_dig) << shift;
            Krem -= s_acc;
            __syncthreads();
        }
        float sum_gt = 0.0f;
        for (int i = tid; i < Np; i += SELTPB) {
            unsigned u = sv[i];
            if (u > prefix) sum_gt += __uint_as_float(u);
        }
        for (int off = 32; off; off >>= 1) sum_gt += __shfl_down(sum_gt, off);
        if (lane == 0) s_f[wv] = sum_gt;
        __syncthreads();
        if (tid == 0) {
            float t = 0.0f;
            for (int w = 0; w < SELWAVES; ++w) t += s_f[w];
            lossc += t + (float)Krem * __uint_as_float(prefix);
        }
    }
    if (tid == 0) {
        row_res[(size_t)b * 3 + 0] = s_lossl;
        row_res[(size_t)b * 3 + 1] = lossc;
        row_res[(size_t)b * 3 + 2] = (float)npos;
    }
}

__global__ __launch_bounds__(TPB) void finalize_kernel(
    const float* __restrict__ row_res, float* __restrict__ out, int B) {
    int tid = threadIdx.x;
    float l = 0, c = 0, n = 0;
    for (int i = tid; i < B; i += TPB) {
        l += row_res[(size_t)i * 3 + 0];
        c += row_res[(size_t)i * 3 + 1];
        n += row_res[(size_t)i * 3 + 2];
    }
    __shared__ float sl[4], sc[4], sn[4];
    for (int off = 32; off; off >>= 1) {
        l += __shfl_down(l, off);
        c += __shfl_down(c, off);
        n += __shfl_down(n, off);
    }
    int lane = tid & 63, w = tid >> 6;
    if (lane == 0) { sl[w] = l; sc[w] = c; sn[w] = n; }
    __syncthreads();
    if (tid == 0) {
        l = sl[0] + sl[1] + sl[2] + sl[3];
        c = sc[0] + sc[1] + sc[2] + sc[3];
        n = sn[0] + sn[1] + sn[2] + sn[3];
        out[0] = l / n;
        out[1] = c / n;
    }
}

extern "C" void kernel_launch(void* const* d_in, const int* in_sizes, int n_in,
                              void* d_out, int out_size, void* d_ws, size_t ws_size,
                              hipStream_t stream) {
    const float* loc = (const float*)d_in[0];
    const float* conf = (const float*)d_in[1];
    const float* dbox = (const float*)d_in[2];
    const float* targets = (const float*)d_in[3];

    int Np = in_sizes[2] / 4;
    int B = in_sizes[0] / (Np * 4);
    int C = in_sizes[1] / (B * Np);
    int No = in_sizes[3] / (B * 5);
    int nchunk = (Np + TPB - 1) / TPB;

    char* w = (char*)d_ws;
    unsigned long long* pkeys = (unsigned long long*)w;
    w += (size_t)B * NMB * No * sizeof(unsigned long long);
    float* tmeta = (float*)w;
    w += (size_t)B * MAXNO * 8 * sizeof(float);
    float* v = (float*)w;
    w += (size_t)B * Np * sizeof(float);
    float* part_l = (float*)w;
    w += (size_t)B * nchunk * sizeof(float);
    float* part_c = (float*)w;
    w += (size_t)B * nchunk * sizeof(float);
    int* part_n = (int*)w;
    w += (size_t)B * nchunk * sizeof(int);
    float* row_res = (float*)w;

    dim3 mgrid(NMB, B);
    if (No == 16)
        match_partial_kernel<16><<<mgrid, 256, 0, stream>>>(dbox, targets, pkeys, Np, No);
    else
        match_partial_kernel<MAXNO><<<mgrid, 256, 0, stream>>>(dbox, targets, pkeys, Np, No);

    combine_kernel<<<B, 64, 0, stream>>>(pkeys, targets, tmeta, No);

    dim3 grid(nchunk, B);
    size_t lds_main = (size_t)TPB * C * sizeof(float);
    if (C == 21 && No == 16)
        main_kernel<21, 16><<<grid, TPB, lds_main, stream>>>(loc, conf, dbox, tmeta,
                                                             v, part_l, part_c, part_n, Np, C, No, nchunk);
    else
        main_kernel<0, 0><<<grid, TPB, lds_main, stream>>>(loc, conf, dbox, tmeta,
                                                           v, part_l, part_c, part_n, Np, C, No, nchunk);
    select_kernel<<<B, SELTPB, (size_t)Np * sizeof(float), stream>>>(v, part_l, part_c, part_n,
                                                                     row_res, Np, nchunk, 3);
    finalize_kernel<<<1, TPB, 0, stream>>>(row_res, (float*)d_out, B);
}

// Round 8
// 84.240 us; speedup vs baseline: 1.0570x; 1.0570x over previous
//
#include <hip/hip_runtime.h>
#include <stdint.h>

#define TPB 256
#define PPT 4
#define SELTPB 1024
#define SELWAVES (SELTPB / 64)
#define MAXNO 64
#define NMB 16  // match chunks per batch row

__device__ __forceinline__ float sl1f(float d) {
    float ad = fabsf(d);
    return ad < 1.0f ? 0.5f * d * d : ad - 0.5f;
}

__device__ __forceinline__ float iou_pair(float tx1, float ty1, float tx2, float ty2, float ta,
                                          float px1, float py1, float px2, float py2, float pa) {
    float ltx = fmaxf(tx1, px1), lty = fmaxf(ty1, py1);
    float rbx = fminf(tx2, px2), rby = fminf(ty2, py2);
    float wx = fmaxf(rbx - ltx, 0.0f), wy = fmaxf(rby - lty, 0.0f);
    float inter = wx * wy;
    return inter / ((ta + pa) - inter);
}

// Kernel A: per (b, chunk) partial argmax over that chunk's priors.
// key = (float_bits(iou) << 32) | (0xFFFFFFFF - p)  => max iou, tie -> min p.
template <int NO>
__global__ __launch_bounds__(256) void match_partial_kernel(
    const float* __restrict__ dbox, const float* __restrict__ targets,
    unsigned long long* __restrict__ pkeys, int Np, int No) {
    int b = blockIdx.y, mb = blockIdx.x;
    int tid = threadIdx.x;
    __shared__ float s_t[NO][5];  // x1,y1,x2,y2,area
    __shared__ unsigned long long s_k[4][NO];
    if (tid < No) {
        const float* tr = targets + ((size_t)b * No + tid) * 5;
        float x1 = tr[0], y1 = tr[1], x2 = tr[2], y2 = tr[3];
        s_t[tid][0] = x1; s_t[tid][1] = y1; s_t[tid][2] = x2; s_t[tid][3] = y2;
        s_t[tid][4] = (x2 - x1) * (y2 - y1);
    }
    __syncthreads();
    int clen = (Np + NMB - 1) / NMB;
    int start = mb * clen;
    int end = start + clen;
    if (end > Np) end = Np;
    unsigned long long key[NO];
#pragma unroll
    for (int t = 0; t < NO; ++t) key[t] = 0ull;
    for (int p = start + tid; p < end; p += 256) {
        float4 pr = *reinterpret_cast<const float4*>(dbox + (size_t)p * 4);
        float px1 = pr.x - pr.z * 0.5f, py1 = pr.y - pr.w * 0.5f;
        float px2 = pr.x + pr.z * 0.5f, py2 = pr.y + pr.w * 0.5f;
        float pa = (px2 - px1) * (py2 - py1);
        unsigned lowp = 0xFFFFFFFFu - (unsigned)p;
#pragma unroll
        for (int t = 0; t < NO; ++t) {
            float iou = iou_pair(s_t[t][0], s_t[t][1], s_t[t][2], s_t[t][3], s_t[t][4],
                                 px1, py1, px2, py2, pa);
            unsigned long long k =
                (((unsigned long long)__float_as_uint(iou)) << 32) | (unsigned long long)lowp;
            if (k > key[t]) key[t] = k;
        }
    }
    int lane = tid & 63, wv = tid >> 6;
#pragma unroll
    for (int t = 0; t < NO; ++t) {
        unsigned long long k = key[t];
        for (int off = 32; off; off >>= 1) {
            unsigned long long o = __shfl_down(k, off);
            if (o > k) k = o;
        }
        if (lane == 0) s_k[wv][t] = k;
    }
    __syncthreads();
    if (tid < No) {
        unsigned long long m = s_k[0][tid];
#pragma unroll
        for (int w = 1; w < 4; ++w)
            if (s_k[w][tid] > m) m = s_k[w][tid];
        pkeys[((size_t)b * NMB + mb) * No + tid] = m;
    }
}

// Kernel A2: fold partials and pack per-truth metadata (32B record):
// {x1,y1,x2,y2,area,label,ovr_prior(bits),0}.
__global__ __launch_bounds__(64) void combine_kernel(
    const unsigned long long* __restrict__ pkeys, const float* __restrict__ targets,
    float* __restrict__ tmeta, int No) {
    int b = blockIdx.x, t = threadIdx.x;
    if (t >= No) return;
    unsigned long long k = pkeys[((size_t)b * NMB + 0) * No + t];
    for (int m = 1; m < NMB; ++m) {
        unsigned long long kk = pkeys[((size_t)b * NMB + m) * No + t];
        if (kk > k) k = kk;
    }
    const float* tr = targets + ((size_t)b * No + t) * 5;
    float x1 = tr[0], y1 = tr[1], x2 = tr[2], y2 = tr[3];
    float* tm = tmeta + ((size_t)b * MAXNO + t) * 8;
    tm[0] = x1; tm[1] = y1; tm[2] = x2; tm[3] = y2;
    tm[4] = (x2 - x1) * (y2 - y1);
    tm[5] = tr[4];
    tm[6] = __uint_as_float(0xFFFFFFFFu - (unsigned)(k & 0xFFFFFFFFull));
    tm[7] = 0.0f;
}

// Kernel B (main): PPT priors per thread; conf rows read DIRECTLY from global
// (no LDS staging, no staging barrier); truth metadata via uniform loads.
template <int CC, int TNO>
__global__ __launch_bounds__(TPB) void main_kernel(
    const float* __restrict__ loc, const float* __restrict__ conf,
    const float* __restrict__ dbox, const float* __restrict__ tmeta,
    float* __restrict__ v, float* __restrict__ part_l, float* __restrict__ part_c,
    int* __restrict__ part_n, int Np, int C, int No, int nchunk) {
    __shared__ float s_tb[MAXNO][5];  // x1,y1,x2,y2,label (divergent gather only)
    __shared__ float s_red1[4];
    __shared__ float s_red2[4];
    __shared__ int s_redi[4];
    int b = blockIdx.y, chunk = blockIdx.x, tid = threadIdx.x;
    int pbase = chunk * (TPB * PPT);
    if (tid < No) {
        const float* tm = tmeta + ((size_t)b * MAXNO + tid) * 8;
        s_tb[tid][0] = tm[0]; s_tb[tid][1] = tm[1];
        s_tb[tid][2] = tm[2]; s_tb[tid][3] = tm[3];
        s_tb[tid][4] = tm[5];
    }
    __syncthreads();

    float lossl = 0.0f, posce = 0.0f;
    int npos = 0;
#pragma unroll 1
    for (int pp = 0; pp < PPT; ++pp) {
        int p = pbase + pp * TPB + tid;
        if (p >= Np) break;
        float4 pr = *reinterpret_cast<const float4*>(dbox + (size_t)p * 4);
        float px1 = pr.x - pr.z * 0.5f, py1 = pr.y - pr.w * 0.5f;
        float px2 = pr.x + pr.z * 0.5f, py2 = pr.y + pr.w * 0.5f;
        float pa = (px2 - px1) * (py2 - py1);
        float bov = -1.0f;
        int bidx = 0;
        int ovt = -1;
        if (TNO > 0) {
#pragma unroll
            for (int t = 0; t < TNO; ++t) {
                const float* tm = tmeta + ((size_t)b * MAXNO + t) * 8;  // uniform -> s_load
                float iou = iou_pair(tm[0], tm[1], tm[2], tm[3], tm[4],
                                     px1, py1, px2, py2, pa);
                if (iou > bov) { bov = iou; bidx = t; }  // strict > : first occurrence
                if (__float_as_uint(tm[6]) == (unsigned)p) ovt = t;  // last match wins
            }
        } else {
            for (int t = 0; t < No; ++t) {
                const float* tm = tmeta + ((size_t)b * MAXNO + t) * 8;
                float iou = iou_pair(tm[0], tm[1], tm[2], tm[3], tm[4],
                                     px1, py1, px2, py2, pa);
                if (iou > bov) { bov = iou; bidx = t; }
                if (__float_as_uint(tm[6]) == (unsigned)p) ovt = t;
            }
        }
        if (ovt >= 0) { bidx = ovt; bov = 2.0f; }
        int ct = (bov < 0.5f) ? 0 : ((int)s_tb[bidx][4] + 1);
        float ce;
        const float* crow = conf + ((size_t)b * Np + p) * C;
        if (CC > 0) {
            float fr[CC > 0 ? CC : 1];
            float mx = -1e30f, fc = 0.0f;
#pragma unroll
            for (int j = 0; j < CC; ++j) {
                float x = crow[j];
                fr[j] = x;
                mx = fmaxf(mx, x);
                fc = (j == ct) ? x : fc;  // static-indexed select, no scratch
            }
            float s = 0.0f;
#pragma unroll
            for (int j = 0; j < CC; ++j) s += __expf(fr[j] - mx);
            ce = __logf(s) + mx - fc;
        } else {
            float mx = crow[0];
            for (int j = 1; j < C; ++j) mx = fmaxf(mx, crow[j]);
            float s = 0.0f;
            for (int j = 0; j < C; ++j) s += __expf(crow[j] - mx);
            ce = __logf(s) + mx - crow[ct];
        }
        bool pos = ct > 0;
        v[(size_t)b * Np + p] = pos ? 0.0f : ce;
        if (pos) {
            posce += ce;
            npos += 1;
            float mx1 = s_tb[bidx][0], my1 = s_tb[bidx][1];
            float mx2 = s_tb[bidx][2], my2 = s_tb[bidx][3];
            float gcx = ((mx1 + mx2) * 0.5f - pr.x) / (0.1f * pr.z);
            float gcy = ((my1 + my2) * 0.5f - pr.y) / (0.1f * pr.w);
            float gw = __logf((mx2 - mx1) / pr.z) / 0.2f;
            float gh = __logf((my2 - my1) / pr.w) / 0.2f;
            float4 l4 = *reinterpret_cast<const float4*>(loc + ((size_t)b * Np + p) * 4);
            lossl += sl1f(l4.x - gcx) + sl1f(l4.y - gcy) + sl1f(l4.z - gw) + sl1f(l4.w - gh);
        }
    }
    // single fused fixed-order block reduction (deterministic)
    float a1 = lossl, a2 = posce;
    int ni = npos;
    for (int off = 32; off; off >>= 1) {
        a1 += __shfl_down(a1, off);
        a2 += __shfl_down(a2, off);
        ni += __shfl_down(ni, off);
    }
    if ((tid & 63) == 0) {
        s_red1[tid >> 6] = a1;
        s_red2[tid >> 6] = a2;
        s_redi[tid >> 6] = ni;
    }
    __syncthreads();
    if (tid == 0) {
        part_l[(size_t)b * nchunk + chunk] = s_red1[0] + s_red1[1] + s_red1[2] + s_red1[3];
        part_c[(size_t)b * nchunk + chunk] = s_red2[0] + s_red2[1] + s_red2[2] + s_red2[3];
        part_n[(size_t)b * nchunk + chunk] = s_redi[0] + s_redi[1] + s_redi[2] + s_redi[3];
    }
}

// Kernel C: per row b -- radix-select the K-th largest float-bits threshold over v,
// then loss_c = posce + sum_{v > T} v + Krem * T.
// Digit find via single-wave shfl suffix scan (3 barriers/pass instead of ~20).
__global__ __launch_bounds__(SELTPB) void select_kernel(
    const float* __restrict__ v, const float* __restrict__ pl,
    const float* __restrict__ pc, const int* __restrict__ pn,
    float* __restrict__ row_res, int Np, int nchunk, int negpos) {
    int b = blockIdx.x, tid = threadIdx.x;
    int lane = tid & 63, wv = tid >> 6;
    extern __shared__ unsigned sv[];  // Np
    __shared__ unsigned whist[SELWAVES][256];  // per-wave privatized hist (16 KB)
    __shared__ float s_f[SELWAVES];
    __shared__ int s_dig, s_acc;
    __shared__ float s_lossl, s_posce;
    __shared__ int s_np;

    if (wv == 0) {
        float a = 0.0f, c = 0.0f;
        int n = 0;
        for (int i = lane; i < nchunk; i += 64) {
            a += pl[(size_t)b * nchunk + i];
            c += pc[(size_t)b * nchunk + i];
            n += pn[(size_t)b * nchunk + i];
        }
        for (int off = 32; off; off >>= 1) {
            a += __shfl_down(a, off);
            c += __shfl_down(c, off);
            n += __shfl_down(n, off);
        }
        if (lane == 0) { s_lossl = a; s_posce = c; s_np = n; }
    }
    {
        const float4* v4 = reinterpret_cast<const float4*>(v + (size_t)b * Np);
        int n4 = Np >> 2;
        for (int i = tid; i < n4; i += SELTPB) {
            float4 f = v4[i];
            uint4 u;
            u.x = __float_as_uint(f.x); u.y = __float_as_uint(f.y);
            u.z = __float_as_uint(f.z); u.w = __float_as_uint(f.w);
            *reinterpret_cast<uint4*>(&sv[i << 2]) = u;
        }
        for (int i = (n4 << 2) + tid; i < Np; i += SELTPB)
            sv[i] = __float_as_uint(v[(size_t)b * Np + i]);
    }
    __syncthreads();
    int npos = s_np;
    int K = npos * negpos;
    if (K > Np) K = Np;
    float lossc = s_posce;
    if (K > 0) {
        unsigned prefix = 0;
        int Krem = K;
        for (int shift = 24; shift >= 0; shift -= 8) {
            for (int i = tid; i < SELWAVES * 256; i += SELTPB)
                (&whist[0][0])[i] = 0;
            __syncthreads();
            for (int i = tid; i < Np; i += SELTPB) {
                unsigned u = sv[i];
                bool match = (shift == 24) || ((u >> (shift + 8)) == (prefix >> (shift + 8)));
                if (match) atomicAdd(&whist[wv][(u >> shift) & 0xFFu], 1u);
            }
            __syncthreads();
            if (wv == 0) {
                // lane L covers bins [4L, 4L+4)
                unsigned t0 = 0, t1 = 0, t2 = 0, t3 = 0;
#pragma unroll
                for (int w = 0; w < SELWAVES; ++w) {
                    t0 += whist[w][4 * lane + 0];
                    t1 += whist[w][4 * lane + 1];
                    t2 += whist[w][4 * lane + 2];
                    t3 += whist[w][4 * lane + 3];
                }
                unsigned s = t0 + t1 + t2 + t3;
                unsigned run = s;  // inclusive suffix over lanes
                for (int off = 1; off < 64; off <<= 1) {
                    unsigned o = __shfl_down(run, off);
                    if (lane + off < 64) run += o;
                }
                unsigned hi = run - s;  // sum over lanes > L
                unsigned S3 = hi + t3, S2 = S3 + t2, S1 = S2 + t1, S0 = S1 + t0;
                unsigned kr = (unsigned)Krem;
                if (S3 >= kr && hi < kr) { s_dig = 4 * lane + 3; s_acc = (int)hi; }
                else if (S2 >= kr && S3 < kr) { s_dig = 4 * lane + 2; s_acc = (int)S3; }
                else if (S1 >= kr && S2 < kr) { s_dig = 4 * lane + 1; s_acc = (int)S2; }
                else if (S0 >= kr && S1 < kr) { s_dig = 4 * lane + 0; s_acc = (int)S1; }
            }
            __syncthreads();
            prefix |= ((unsigned)s_dig) << shift;
            Krem -= s_acc;
        }
        float sum_gt = 0.0f;
        for (int i = tid; i < Np; i += SELTPB) {
            unsigned u = sv[i];
            if (u > prefix) sum_gt += __uint_as_float(u);
        }
        for (int off = 32; off; off >>= 1) sum_gt += __shfl_down(sum_gt, off);
        if (lane == 0) s_f[wv] = sum_gt;
        __syncthreads();
        if (tid == 0) {
            float t = 0.0f;
            for (int w = 0; w < SELWAVES; ++w) t += s_f[w];
            lossc += t + (float)Krem * __uint_as_float(prefix);
        }
    }
    if (tid == 0) {
        row_res[(size_t)b * 3 + 0] = s_lossl;
        row_res[(size_t)b * 3 + 1] = lossc;
        row_res[(size_t)b * 3 + 2] = (float)npos;
    }
}

__global__ __launch_bounds__(TPB) void finalize_kernel(
    const float* __restrict__ row_res, float* __restrict__ out, int B) {
    int tid = threadIdx.x;
    float l = 0, c = 0, n = 0;
    for (int i = tid; i < B; i += TPB) {
        l += row_res[(size_t)i * 3 + 0];
        c += row_res[(size_t)i * 3 + 1];
        n += row_res[(size_t)i * 3 + 2];
    }
    __shared__ float sl[4], sc[4], sn[4];
    for (int off = 32; off; off >>= 1) {
        l += __shfl_down(l, off);
        c += __shfl_down(c, off);
        n += __shfl_down(n, off);
    }
    int lane = tid & 63, w = tid >> 6;
    if (lane == 0) { sl[w] = l; sc[w] = c; sn[w] = n; }
    __syncthreads();
    if (tid == 0) {
        l = sl[0] + sl[1] + sl[2] + sl[3];
        c = sc[0] + sc[1] + sc[2] + sc[3];
        n = sn[0] + sn[1] + sn[2] + sn[3];
        out[0] = l / n;
        out[1] = c / n;
    }
}

extern "C" void kernel_launch(void* const* d_in, const int* in_sizes, int n_in,
                              void* d_out, int out_size, void* d_ws, size_t ws_size,
                              hipStream_t stream) {
    const float* loc = (const float*)d_in[0];
    const float* conf = (const float*)d_in[1];
    const float* dbox = (const float*)d_in[2];
    const float* targets = (const float*)d_in[3];

    int Np = in_sizes[2] / 4;
    int B = in_sizes[0] / (Np * 4);
    int C = in_sizes[1] / (B * Np);
    int No = in_sizes[3] / (B * 5);
    int nchunk = (Np + TPB * PPT - 1) / (TPB * PPT);

    char* w = (char*)d_ws;
    unsigned long long* pkeys = (unsigned long long*)w;
    w += (size_t)B * NMB * No * sizeof(unsigned long long);
    float* tmeta = (float*)w;
    w += (size_t)B * MAXNO * 8 * sizeof(float);
    float* v = (float*)w;
    w += (size_t)B * Np * sizeof(float);
    float* part_l = (float*)w;
    w += (size_t)B * nchunk * sizeof(float);
    float* part_c = (float*)w;
    w += (size_t)B * nchunk * sizeof(float);
    int* part_n = (int*)w;
    w += (size_t)B * nchunk * sizeof(int);
    float* row_res = (float*)w;

    dim3 mgrid(NMB, B);
    if (No == 16)
        match_partial_kernel<16><<<mgrid, 256, 0, stream>>>(dbox, targets, pkeys, Np, No);
    else
        match_partial_kernel<MAXNO><<<mgrid, 256, 0, stream>>>(dbox, targets, pkeys, Np, No);

    combine_kernel<<<B, 64, 0, stream>>>(pkeys, targets, tmeta, No);

    dim3 grid(nchunk, B);
    if (C == 21 && No == 16)
        main_kernel<21, 16><<<grid, TPB, 0, stream>>>(loc, conf, dbox, tmeta,
                                                      v, part_l, part_c, part_n, Np, C, No, nchunk);
    else
        main_kernel<0, 0><<<grid, TPB, 0, stream>>>(loc, conf, dbox, tmeta,
                                                    v, part_l, part_c, part_n, Np, C, No, nchunk);
    select_kernel<<<B, SELTPB, (size_t)Np * sizeof(float), stream>>>(v, part_l, part_c, part_n,
                                                                     row_res, Np, nchunk, 3);
    finalize_kernel<<<1, TPB, 0, stream>>>(row_res, (float*)d_out, B);
}